// Round 1
// baseline (340.407 us; speedup 1.0000x reference)
//
#include <hip/hip_runtime.h>
#include <hip/hip_bf16.h>

// GCN layer: out[col] += (x@W)[row] * dis[row]*dis[col], + self loops + bias
// N=50000 nodes, E=800000 edges, D=64 features in/out, all fp32.
// Baseline structure: atomic-scatter version (correctness-first).

constexpr int N_NODES = 50000;
constexpr int N_EDGES = 800000;
constexpr int D = 64;

// ---- 1. degree histogram over row ----
__global__ void deg_kernel(const int* __restrict__ row, float* __restrict__ deg) {
    int e = blockIdx.x * blockDim.x + threadIdx.x;
    if (e < N_EDGES) {
        atomicAdd(&deg[row[e]], 1.0f);
    }
}

// ---- 2. dis[i] = rsqrt(deg[i] + 1)  (self loop => deg always > 0) ----
__global__ void dis_kernel(float* __restrict__ deg) {
    int i = blockIdx.x * blockDim.x + threadIdx.x;
    if (i < N_NODES) {
        deg[i] = rsqrtf(deg[i] + 1.0f);
    }
}

// ---- 3. h = x @ W  (W staged in LDS; one thread per output element) ----
__global__ void gemm_kernel(const float* __restrict__ x,
                            const float* __restrict__ W,
                            float* __restrict__ h) {
    __shared__ float Ws[D * D];  // 16 KB
    for (int i = threadIdx.x; i < D * D; i += blockDim.x) Ws[i] = W[i];
    __syncthreads();

    int gid = blockIdx.x * blockDim.x + threadIdx.x;
    if (gid >= N_NODES * D) return;
    int n = gid >> 6;
    int j = gid & 63;
    const float* xr = x + n * D;
    float acc = 0.0f;
#pragma unroll
    for (int k = 0; k < D; ++k) {
        acc = fmaf(xr[k], Ws[k * D + j], acc);
    }
    h[gid] = acc;
}

// ---- 4. out = bias + h * dis^2  (self-loop contribution; also zero-inits out) ----
__global__ void init_out_kernel(const float* __restrict__ h,
                                const float* __restrict__ dis,
                                const float* __restrict__ bias,
                                float* __restrict__ out) {
    int gid = blockIdx.x * blockDim.x + threadIdx.x;
    if (gid >= N_NODES * D) return;
    int n = gid >> 6;
    int j = gid & 63;
    float d = dis[n];
    out[gid] = bias[j] + h[gid] * d * d;
}

// ---- 5. edge scatter: 64 lanes per edge, atomicAdd into out[col] ----
__global__ void scatter_kernel(const int* __restrict__ row,
                               const int* __restrict__ col,
                               const float* __restrict__ h,
                               const float* __restrict__ dis,
                               float* __restrict__ out) {
    long long gid = (long long)blockIdx.x * blockDim.x + threadIdx.x;
    int e = (int)(gid >> 6);
    int j = (int)(gid & 63);
    if (e < N_EDGES) {
        int r = row[e];
        int c = col[e];
        float norm = dis[r] * dis[c];  // wave-uniform (whole wave = same edge? no: 4 edges/wave, but uniform per 64-thread group spanning... lanes 0..63 of a 256-block cover 4 edges; loads broadcast within each 64-lane slice via L1)
        atomicAdd(&out[c * D + j], h[r * D + j] * norm);
    }
}

extern "C" void kernel_launch(void* const* d_in, const int* in_sizes, int n_in,
                              void* d_out, int out_size, void* d_ws, size_t ws_size,
                              hipStream_t stream) {
    const float* x    = (const float*)d_in[0];
    const int*   ei   = (const int*)d_in[1];
    const float* W    = (const float*)d_in[2];
    const float* bias = (const float*)d_in[3];
    float* out = (float*)d_out;

    const int* row = ei;            // edge_index[0]
    const int* col = ei + N_EDGES;  // edge_index[1]

    // workspace layout: [deg/dis: 50176 floats][h: N*D floats]  ~13 MB
    float* deg = (float*)d_ws;
    float* h   = (float*)((char*)d_ws + 50176 * sizeof(float));

    hipMemsetAsync(deg, 0, N_NODES * sizeof(float), stream);

    deg_kernel<<<(N_EDGES + 255) / 256, 256, 0, stream>>>(row, deg);
    dis_kernel<<<(N_NODES + 255) / 256, 256, 0, stream>>>(deg);
    gemm_kernel<<<(N_NODES * D + 255) / 256, 256, 0, stream>>>(x, W, h);
    init_out_kernel<<<(N_NODES * D + 255) / 256, 256, 0, stream>>>(h, deg, bias, out);

    long long total = (long long)N_EDGES * D;
    scatter_kernel<<<(int)((total + 255) / 256), 256, 0, stream>>>(row, col, h, deg, out);
}

// Round 2
// 281.314 us; speedup vs baseline: 1.2101x; 1.2101x over previous
//
#include <hip/hip_runtime.h>
#include <hip/hip_bf16.h>

// GCN layer: out[c] = bias + h[c]*dis[c]^2 + sum_{e:col=c} h[row_e]*dis[row_e]*dis[c]
// N=50000, E=800000, D=64, fp32.
// R2: CSR-by-col build + wave-per-node gather (no output atomics).

constexpr int N_NODES = 50000;
constexpr int N_EDGES = 800000;
constexpr int D = 64;
constexpr int NB_SCAN = (N_NODES + 255) / 256;  // 196

// ---- 1. fused histograms: degree over row (for norm), count over col (for CSR) ----
__global__ void hist_kernel(const int* __restrict__ row, const int* __restrict__ col,
                            int* __restrict__ degi, int* __restrict__ cnt) {
    int e = blockIdx.x * blockDim.x + threadIdx.x;
    if (e < N_EDGES) {
        atomicAdd(&degi[row[e]], 1);
        atomicAdd(&cnt[col[e]], 1);
    }
}

// ---- 2. dis[i] = rsqrt(degi[i] + 1), in place (int -> float reuse) ----
__global__ void dis_kernel(int* __restrict__ degi) {
    int i = blockIdx.x * blockDim.x + threadIdx.x;
    if (i < N_NODES) {
        float d = (float)degi[i] + 1.0f;  // +1 self loop
        ((float*)degi)[i] = rsqrtf(d);
    }
}

// ---- 3a. per-block exclusive scan of cnt -> offs, block totals -> partials ----
__global__ void block_scan_kernel(const int* __restrict__ cnt, int* __restrict__ offs,
                                  int* __restrict__ partials) {
    __shared__ int s[256];
    int t = threadIdx.x;
    int i = blockIdx.x * 256 + t;
    int v = (i < N_NODES) ? cnt[i] : 0;
    s[t] = v;
    __syncthreads();
    for (int d = 1; d < 256; d <<= 1) {
        int u = (t >= d) ? s[t - d] : 0;
        __syncthreads();
        s[t] += u;
        __syncthreads();
    }
    if (i < N_NODES) offs[i] = s[t] - v;  // exclusive
    if (t == 255) partials[blockIdx.x] = s[t];  // inclusive total
}

// ---- 3b. scan the 196 block totals (single block) ----
__global__ void scan_partials_kernel(int* __restrict__ partials) {
    __shared__ int s[256];
    int t = threadIdx.x;
    int v = (t < NB_SCAN) ? partials[t] : 0;
    s[t] = v;
    __syncthreads();
    for (int d = 1; d < 256; d <<= 1) {
        int u = (t >= d) ? s[t - d] : 0;
        __syncthreads();
        s[t] += u;
        __syncthreads();
    }
    if (t < NB_SCAN) partials[t] = s[t] - v;  // exclusive
}

// ---- 3c. add block offsets ----
__global__ void add_off_kernel(int* __restrict__ offs, const int* __restrict__ partials) {
    int i = blockIdx.x * 256 + threadIdx.x;
    if (i < N_NODES) offs[i] += partials[blockIdx.x];
}

// ---- 4. bucket edges into CSR: csr[pos] = {row, dis[row]*dis[col]} ----
__global__ void bucket_kernel(const int* __restrict__ row, const int* __restrict__ col,
                              const float* __restrict__ dis,
                              const int* __restrict__ offs, int* __restrict__ cur,
                              int2* __restrict__ csr) {
    int e = blockIdx.x * blockDim.x + threadIdx.x;
    if (e < N_EDGES) {
        int r = row[e];
        int c = col[e];
        int pos = offs[c] + atomicAdd(&cur[c], 1);
        float norm = dis[r] * dis[c];
        csr[pos] = make_int2(r, __float_as_int(norm));
    }
}

// ---- 5. h = x @ W  (W staged in LDS; one thread per output element) ----
__global__ void gemm_kernel(const float* __restrict__ x,
                            const float* __restrict__ W,
                            float* __restrict__ h) {
    __shared__ float Ws[D * D];  // 16 KB
    for (int i = threadIdx.x; i < D * D; i += blockDim.x) Ws[i] = W[i];
    __syncthreads();

    int gid = blockIdx.x * blockDim.x + threadIdx.x;
    if (gid >= N_NODES * D) return;
    int n = gid >> 6;
    int j = gid & 63;
    const float* xr = x + n * D;
    float acc = 0.0f;
#pragma unroll
    for (int k = 0; k < D; ++k) {
        acc = fmaf(xr[k], Ws[k * D + j], acc);
    }
    h[gid] = acc;
}

// ---- 6. gather: one wave per node, lane = feature; fuses bias + self loop ----
__global__ void gather_kernel(const int* __restrict__ offs, const int* __restrict__ cnt,
                              const int2* __restrict__ csr,
                              const float* __restrict__ h, const float* __restrict__ dis,
                              const float* __restrict__ bias,
                              float* __restrict__ out) {
    int wave = threadIdx.x >> 6;
    int j = threadIdx.x & 63;
    int n = blockIdx.x * 4 + wave;
    if (n >= N_NODES) return;

    float d = dis[n];
    float acc = bias[j] + h[n * D + j] * d * d;  // self-loop term

    int beg = offs[n];
    int m = cnt[n];
    for (int base = 0; base < m; base += 64) {
        int take = min(64, m - base);
        int2 e = make_int2(0, 0);
        if (j < take) e = csr[beg + base + j];  // coalesced batch load
        for (int i = 0; i < take; ++i) {
            int r = __shfl(e.x, i);
            float norm = __int_as_float(__shfl(e.y, i));
            acc = fmaf(h[r * D + j], norm, acc);  // coalesced 256B row read
        }
    }
    out[n * D + j] = acc;
}

extern "C" void kernel_launch(void* const* d_in, const int* in_sizes, int n_in,
                              void* d_out, int out_size, void* d_ws, size_t ws_size,
                              hipStream_t stream) {
    const float* x    = (const float*)d_in[0];
    const int*   ei   = (const int*)d_in[1];
    const float* W    = (const float*)d_in[2];
    const float* bias = (const float*)d_in[3];
    float* out = (float*)d_out;

    const int* row = ei;            // edge_index[0]
    const int* col = ei + N_EDGES;  // edge_index[1]

    // workspace layout (bytes):
    //   [0      .. 200000)  degi / dis (int->float in place)
    //   [200000 .. 400000)  cnt
    //   [400000 .. 600000)  cur
    //   [600000 .. 800000)  offs
    //   [800000 .. 801024)  partials (256 ints)
    //   [801024 .. 7201024) csr (800000 x int2)
    //   [7201024 .. 20001024) h (N*D floats)
    char* ws = (char*)d_ws;
    int*   degi     = (int*)(ws + 0);
    int*   cnt      = (int*)(ws + 200000);
    int*   cur      = (int*)(ws + 400000);
    int*   offs     = (int*)(ws + 600000);
    int*   partials = (int*)(ws + 800000);
    int2*  csr      = (int2*)(ws + 801024);
    float* h        = (float*)(ws + 7201024);
    float* dis      = (float*)degi;

    hipMemsetAsync(ws, 0, 600000, stream);  // degi + cnt + cur

    hist_kernel<<<(N_EDGES + 255) / 256, 256, 0, stream>>>(row, col, degi, cnt);
    dis_kernel<<<(N_NODES + 255) / 256, 256, 0, stream>>>(degi);
    block_scan_kernel<<<NB_SCAN, 256, 0, stream>>>(cnt, offs, partials);
    scan_partials_kernel<<<1, 256, 0, stream>>>(partials);
    add_off_kernel<<<NB_SCAN, 256, 0, stream>>>(offs, partials);
    bucket_kernel<<<(N_EDGES + 255) / 256, 256, 0, stream>>>(row, col, dis, offs, cur, csr);
    gemm_kernel<<<(N_NODES * D + 255) / 256, 256, 0, stream>>>(x, W, h);
    gather_kernel<<<(N_NODES + 3) / 4, 256, 0, stream>>>(offs, cnt, csr, h, dis, bias, out);
}

// Round 3
// 220.036 us; speedup vs baseline: 1.5471x; 1.2785x over previous
//
#include <hip/hip_runtime.h>
#include <hip/hip_bf16.h>

// GCN layer: out[c] = bias + h[c]*dis[c]^2 + sum_{e:col=c} h[row_e]*dis[row_e]*dis[c]
// N=50000, E=800000, D=64, fp32.
// R3: atomic-free CSR build (private LDS histograms + deterministic bucketing).
//     Scattered global atomics (hist 65us, bucket ~60us) -> coalesced streaming.

constexpr int N_NODES = 50000;
constexpr int N_EDGES = 800000;
constexpr int D = 64;
constexpr int NB_SCAN = (N_NODES + 255) / 256;  // 196

constexpr int B_SLICE = 64;                  // edge slices
constexpr int SLICE = N_EDGES / B_SLICE;     // 12500 (exact)
constexpr int PACK = N_NODES / 2;            // 25000 packed u16-pair words
constexpr int HALF = 25000;                  // bins per bucket chunk (2 chunks)

// ======================= new atomic-free build path =======================

// ---- A. per-slice private histograms in LDS (u16 packed pairs) ----
// grid 2*B_SLICE: blocks [0,64) histogram row (degrees), [64,128) histogram col.
__global__ __launch_bounds__(1024) void hist_priv_kernel(const int* __restrict__ ei,
                                                         unsigned* __restrict__ bh) {
    __shared__ unsigned loc[PACK];  // 100 KB
    int b = blockIdx.x;
    int s = b & (B_SLICE - 1);
    const int* arr = (b < B_SLICE) ? ei : ei + N_EDGES;
    for (int w = threadIdx.x; w < PACK; w += 1024) loc[w] = 0;
    __syncthreads();
    const int* p = arr + s * SLICE;
    for (int i = threadIdx.x; i < SLICE; i += 1024) {
        int k = p[i];
        atomicAdd(&loc[k >> 1], (k & 1) ? 65536u : 1u);  // LDS atomic
    }
    __syncthreads();
    unsigned* dst = bh + (size_t)b * PACK;
    for (int w = threadIdx.x; w < PACK; w += 1024) dst[w] = loc[w];
}

// ---- B. reduce private histograms -> dis (from row degrees) and cnt (col) ----
__global__ void reduce_kernel(const unsigned* __restrict__ bh,
                              float* __restrict__ dis, int* __restrict__ cnt) {
    int t = blockIdx.x * 256 + threadIdx.x;
    bool is_col = (t >= PACK);
    int w = is_col ? t - PACK : t;
    if (w >= PACK) return;
    const unsigned* src = bh + (is_col ? (size_t)B_SLICE * PACK : 0) + w;
    unsigned lo = 0, hi = 0;
#pragma unroll 4
    for (int b = 0; b < B_SLICE; ++b) {
        unsigned v = src[(size_t)b * PACK];
        lo += v & 0xffffu;
        hi += v >> 16;
    }
    if (!is_col) {
        dis[2 * w]     = rsqrtf((float)lo + 1.0f);  // +1 self loop
        dis[2 * w + 1] = rsqrtf((float)hi + 1.0f);
    } else {
        cnt[2 * w]     = (int)lo;
        cnt[2 * w + 1] = (int)hi;
    }
}

// ---- C. per-bin scan over slices -> per-(slice,bin) start offsets bs ----
__global__ void colscan_kernel(const unsigned* __restrict__ bh,
                               const int* __restrict__ offs, unsigned* __restrict__ bs) {
    int w = blockIdx.x * 256 + threadIdx.x;
    if (w >= PACK) return;
    const unsigned* src = bh + (size_t)B_SLICE * PACK + w;
    unsigned lo = (unsigned)offs[2 * w];
    unsigned hi = (unsigned)offs[2 * w + 1];
    for (int b = 0; b < B_SLICE; ++b) {
        bs[(size_t)b * N_NODES + 2 * w]     = lo;
        bs[(size_t)b * N_NODES + 2 * w + 1] = hi;
        unsigned v = src[(size_t)b * PACK];
        lo += v & 0xffffu;
        hi += v >> 16;
    }
}

// ---- D. deterministic bucket: LDS fetch-add on preloaded start offsets ----
// grid = B_SLICE * 2 (slice x chunk)
__global__ __launch_bounds__(1024) void bucket_det_kernel(const int* __restrict__ ei,
                                                          const float* __restrict__ dis,
                                                          const unsigned* __restrict__ bs,
                                                          int2* __restrict__ csr) {
    __shared__ unsigned pos[HALF];  // 100 KB
    int s = blockIdx.x >> 1;
    int h = blockIdx.x & 1;
    int c0 = h * HALF;
    const unsigned* src = bs + (size_t)s * N_NODES + c0;
    for (int w = threadIdx.x; w < HALF; w += 1024) pos[w] = src[w];
    __syncthreads();
    const int* row = ei + s * SLICE;
    const int* col = ei + N_EDGES + s * SLICE;
    for (int i = threadIdx.x; i < SLICE; i += 1024) {
        int c = col[i];
        if (c >= c0 && c < c0 + HALF) {
            int r = row[i];
            unsigned p = atomicAdd(&pos[c - c0], 1u);  // LDS atomic
            float norm = dis[r] * dis[c];
            csr[p] = make_int2(r, __float_as_int(norm));
        }
    }
}

// ======================= fallback (R2 atomic) build path =======================

__global__ void hist_kernel(const int* __restrict__ row, const int* __restrict__ col,
                            int* __restrict__ degi, int* __restrict__ cnt) {
    int e = blockIdx.x * blockDim.x + threadIdx.x;
    if (e < N_EDGES) {
        atomicAdd(&degi[row[e]], 1);
        atomicAdd(&cnt[col[e]], 1);
    }
}

__global__ void dis_kernel(int* __restrict__ degi) {
    int i = blockIdx.x * blockDim.x + threadIdx.x;
    if (i < N_NODES) {
        float d = (float)degi[i] + 1.0f;
        ((float*)degi)[i] = rsqrtf(d);
    }
}

__global__ void bucket_kernel(const int* __restrict__ row, const int* __restrict__ col,
                              const float* __restrict__ dis,
                              const int* __restrict__ offs, int* __restrict__ cur,
                              int2* __restrict__ csr) {
    int e = blockIdx.x * blockDim.x + threadIdx.x;
    if (e < N_EDGES) {
        int r = row[e];
        int c = col[e];
        int pos = offs[c] + atomicAdd(&cur[c], 1);
        float norm = dis[r] * dis[c];
        csr[pos] = make_int2(r, __float_as_int(norm));
    }
}

// ======================= scan (shared by both paths) =======================

__global__ void block_scan_kernel(const int* __restrict__ cnt, int* __restrict__ offs,
                                  int* __restrict__ partials) {
    __shared__ int s[256];
    int t = threadIdx.x;
    int i = blockIdx.x * 256 + t;
    int v = (i < N_NODES) ? cnt[i] : 0;
    s[t] = v;
    __syncthreads();
    for (int d = 1; d < 256; d <<= 1) {
        int u = (t >= d) ? s[t - d] : 0;
        __syncthreads();
        s[t] += u;
        __syncthreads();
    }
    if (i < N_NODES) offs[i] = s[t] - v;
    if (t == 255) partials[blockIdx.x] = s[t];
}

__global__ void scan_partials_kernel(int* __restrict__ partials) {
    __shared__ int s[256];
    int t = threadIdx.x;
    int v = (t < NB_SCAN) ? partials[t] : 0;
    s[t] = v;
    __syncthreads();
    for (int d = 1; d < 256; d <<= 1) {
        int u = (t >= d) ? s[t - d] : 0;
        __syncthreads();
        s[t] += u;
        __syncthreads();
    }
    if (t < NB_SCAN) partials[t] = s[t] - v;
}

__global__ void add_off_kernel(int* __restrict__ offs, const int* __restrict__ partials) {
    int i = blockIdx.x * 256 + threadIdx.x;
    if (i < N_NODES) offs[i] += partials[blockIdx.x];
}

// ======================= gemm + gather =======================

__global__ void gemm_kernel(const float* __restrict__ x,
                            const float* __restrict__ W,
                            float* __restrict__ h) {
    __shared__ float Ws[D * D];  // 16 KB
    for (int i = threadIdx.x; i < D * D; i += blockDim.x) Ws[i] = W[i];
    __syncthreads();

    int gid = blockIdx.x * blockDim.x + threadIdx.x;
    if (gid >= N_NODES * D) return;
    int n = gid >> 6;
    int j = gid & 63;
    const float* xr = x + n * D;
    float acc = 0.0f;
#pragma unroll
    for (int k = 0; k < D; ++k) {
        acc = fmaf(xr[k], Ws[k * D + j], acc);
    }
    h[gid] = acc;
}

__global__ void gather_kernel(const int* __restrict__ offs, const int* __restrict__ cnt,
                              const int2* __restrict__ csr,
                              const float* __restrict__ h, const float* __restrict__ dis,
                              const float* __restrict__ bias,
                              float* __restrict__ out) {
    int wave = threadIdx.x >> 6;
    int j = threadIdx.x & 63;
    int n = blockIdx.x * 4 + wave;
    if (n >= N_NODES) return;

    float d = dis[n];
    float acc = bias[j] + h[n * D + j] * d * d;  // self-loop term

    int beg = offs[n];
    int m = cnt[n];
    for (int base = 0; base < m; base += 64) {
        int take = min(64, m - base);
        int2 e = make_int2(0, 0);
        if (j < take) e = csr[beg + base + j];
        for (int i = 0; i < take; ++i) {
            int r = __shfl(e.x, i);
            float norm = __int_as_float(__shfl(e.y, i));
            acc = fmaf(h[r * D + j], norm, acc);
        }
    }
    out[n * D + j] = acc;
}

// ======================= launch =======================

extern "C" void kernel_launch(void* const* d_in, const int* in_sizes, int n_in,
                              void* d_out, int out_size, void* d_ws, size_t ws_size,
                              hipStream_t stream) {
    const float* x    = (const float*)d_in[0];
    const int*   ei   = (const int*)d_in[1];
    const float* W    = (const float*)d_in[2];
    const float* bias = (const float*)d_in[3];
    float* out = (float*)d_out;

    const int* row = ei;
    const int* col = ei + N_EDGES;

    // workspace layout (bytes):
    //   [0        ..   200000)  dis (float) / degi (int, fallback)
    //   [200000   ..   400000)  cnt
    //   [400000   ..   600000)  cur (fallback only)
    //   [600000   ..   800000)  offs
    //   [800000   ..   801024)  partials
    //   [801024   ..  7201024)  csr (800000 x int2)
    //   [7201024  .. 20001024)  h (N*D floats)
    //   [20001024 .. 32801024)  bh (128 x 25000 u32)
    //   [32801024 .. 45601024)  bs (64 x 50000 u32)
    char* ws = (char*)d_ws;
    float*    dis      = (float*)(ws + 0);
    int*      cnt      = (int*)(ws + 200000);
    int*      cur      = (int*)(ws + 400000);
    int*      offs     = (int*)(ws + 600000);
    int*      partials = (int*)(ws + 800000);
    int2*     csr      = (int2*)(ws + 801024);
    float*    h        = (float*)(ws + 7201024);
    unsigned* bh       = (unsigned*)(ws + 20001024);
    unsigned* bs       = (unsigned*)(ws + 32801024);

    const size_t WS_NEEDED = 45601024;

    if (ws_size >= WS_NEEDED) {
        // atomic-free build
        hist_priv_kernel<<<2 * B_SLICE, 1024, 0, stream>>>(ei, bh);
        reduce_kernel<<<(2 * PACK + 255) / 256, 256, 0, stream>>>(bh, dis, cnt);
        block_scan_kernel<<<NB_SCAN, 256, 0, stream>>>(cnt, offs, partials);
        scan_partials_kernel<<<1, 256, 0, stream>>>(partials);
        add_off_kernel<<<NB_SCAN, 256, 0, stream>>>(offs, partials);
        colscan_kernel<<<(PACK + 255) / 256, 256, 0, stream>>>(bh, offs, bs);
        bucket_det_kernel<<<2 * B_SLICE, 1024, 0, stream>>>(ei, dis, bs, csr);
    } else {
        // fallback: R2 atomic build
        int* degi = (int*)dis;
        hipMemsetAsync(ws, 0, 600000, stream);
        hist_kernel<<<(N_EDGES + 255) / 256, 256, 0, stream>>>(row, col, degi, cnt);
        dis_kernel<<<(N_NODES + 255) / 256, 256, 0, stream>>>(degi);
        block_scan_kernel<<<NB_SCAN, 256, 0, stream>>>(cnt, offs, partials);
        scan_partials_kernel<<<1, 256, 0, stream>>>(partials);
        add_off_kernel<<<NB_SCAN, 256, 0, stream>>>(offs, partials);
        bucket_kernel<<<(N_EDGES + 255) / 256, 256, 0, stream>>>(row, col, dis, offs, cur, csr);
    }

    gemm_kernel<<<(N_NODES * D + 255) / 256, 256, 0, stream>>>(x, W, h);
    gather_kernel<<<(N_NODES + 3) / 4, 256, 0, stream>>>(offs, cnt, csr, h, dis, bias, out);
}

// Round 4
// 178.850 us; speedup vs baseline: 1.9033x; 1.2303x over previous
//
#include <hip/hip_runtime.h>
#include <hip/hip_bf16.h>

// GCN layer: out[c] = bias + h[c]*dis[c]^2 + sum_{e:col=c} h[row_e]*dis[row_e]*dis[c]
// N=50000, E=800000, D=64, fp32.
// R4: gather unrolled x4 (4 independent loads in flight, 4 accumulators);
//     gemm rewritten as 64x64 LDS tile + 4x4 register tile per thread.

constexpr int N_NODES = 50000;
constexpr int N_EDGES = 800000;
constexpr int D = 64;
constexpr int NB_SCAN = (N_NODES + 255) / 256;  // 196

constexpr int B_SLICE = 64;                  // edge slices
constexpr int SLICE = N_EDGES / B_SLICE;     // 12500 (exact)
constexpr int PACK = N_NODES / 2;            // 25000 packed u16-pair words
constexpr int HALF = 25000;                  // bins per bucket chunk (2 chunks)

// ======================= atomic-free build path =======================

// ---- A. per-slice private histograms in LDS (u16 packed pairs) ----
// grid 2*B_SLICE: blocks [0,64) histogram row (degrees), [64,128) histogram col.
__global__ __launch_bounds__(1024) void hist_priv_kernel(const int* __restrict__ ei,
                                                         unsigned* __restrict__ bh) {
    __shared__ unsigned loc[PACK];  // 100 KB
    int b = blockIdx.x;
    int s = b & (B_SLICE - 1);
    const int* arr = (b < B_SLICE) ? ei : ei + N_EDGES;
    for (int w = threadIdx.x; w < PACK; w += 1024) loc[w] = 0;
    __syncthreads();
    const int* p = arr + s * SLICE;
    for (int i = threadIdx.x; i < SLICE; i += 1024) {
        int k = p[i];
        atomicAdd(&loc[k >> 1], (k & 1) ? 65536u : 1u);  // LDS atomic
    }
    __syncthreads();
    unsigned* dst = bh + (size_t)b * PACK;
    for (int w = threadIdx.x; w < PACK; w += 1024) dst[w] = loc[w];
}

// ---- B. reduce private histograms -> dis (row degrees) and cnt (col) ----
__global__ void reduce_kernel(const unsigned* __restrict__ bh,
                              float* __restrict__ dis, int* __restrict__ cnt) {
    int t = blockIdx.x * 256 + threadIdx.x;
    bool is_col = (t >= PACK);
    int w = is_col ? t - PACK : t;
    if (w >= PACK) return;
    const unsigned* src = bh + (is_col ? (size_t)B_SLICE * PACK : 0) + w;
    unsigned lo = 0, hi = 0;
#pragma unroll 4
    for (int b = 0; b < B_SLICE; ++b) {
        unsigned v = src[(size_t)b * PACK];
        lo += v & 0xffffu;
        hi += v >> 16;
    }
    if (!is_col) {
        dis[2 * w]     = rsqrtf((float)lo + 1.0f);  // +1 self loop
        dis[2 * w + 1] = rsqrtf((float)hi + 1.0f);
    } else {
        cnt[2 * w]     = (int)lo;
        cnt[2 * w + 1] = (int)hi;
    }
}

// ---- C. per-bin scan over slices -> per-(slice,bin) start offsets bs ----
__global__ void colscan_kernel(const unsigned* __restrict__ bh,
                               const int* __restrict__ offs, unsigned* __restrict__ bs) {
    int w = blockIdx.x * 256 + threadIdx.x;
    if (w >= PACK) return;
    const unsigned* src = bh + (size_t)B_SLICE * PACK + w;
    unsigned lo = (unsigned)offs[2 * w];
    unsigned hi = (unsigned)offs[2 * w + 1];
    for (int b = 0; b < B_SLICE; ++b) {
        bs[(size_t)b * N_NODES + 2 * w]     = lo;
        bs[(size_t)b * N_NODES + 2 * w + 1] = hi;
        unsigned v = src[(size_t)b * PACK];
        lo += v & 0xffffu;
        hi += v >> 16;
    }
}

// ---- D. deterministic bucket: LDS fetch-add on preloaded start offsets ----
__global__ __launch_bounds__(1024) void bucket_det_kernel(const int* __restrict__ ei,
                                                          const float* __restrict__ dis,
                                                          const unsigned* __restrict__ bs,
                                                          int2* __restrict__ csr) {
    __shared__ unsigned pos[HALF];  // 100 KB
    int s = blockIdx.x >> 1;
    int hh = blockIdx.x & 1;
    int c0 = hh * HALF;
    const unsigned* src = bs + (size_t)s * N_NODES + c0;
    for (int w = threadIdx.x; w < HALF; w += 1024) pos[w] = src[w];
    __syncthreads();
    const int* row = ei + s * SLICE;
    const int* col = ei + N_EDGES + s * SLICE;
    for (int i = threadIdx.x; i < SLICE; i += 1024) {
        int c = col[i];
        if (c >= c0 && c < c0 + HALF) {
            int r = row[i];
            unsigned p = atomicAdd(&pos[c - c0], 1u);  // LDS atomic
            float norm = dis[r] * dis[c];
            csr[p] = make_int2(r, __float_as_int(norm));
        }
    }
}

// ======================= fallback (atomic) build path =======================

__global__ void hist_kernel(const int* __restrict__ row, const int* __restrict__ col,
                            int* __restrict__ degi, int* __restrict__ cnt) {
    int e = blockIdx.x * blockDim.x + threadIdx.x;
    if (e < N_EDGES) {
        atomicAdd(&degi[row[e]], 1);
        atomicAdd(&cnt[col[e]], 1);
    }
}

__global__ void dis_kernel(int* __restrict__ degi) {
    int i = blockIdx.x * blockDim.x + threadIdx.x;
    if (i < N_NODES) {
        float d = (float)degi[i] + 1.0f;
        ((float*)degi)[i] = rsqrtf(d);
    }
}

__global__ void bucket_kernel(const int* __restrict__ row, const int* __restrict__ col,
                              const float* __restrict__ dis,
                              const int* __restrict__ offs, int* __restrict__ cur,
                              int2* __restrict__ csr) {
    int e = blockIdx.x * blockDim.x + threadIdx.x;
    if (e < N_EDGES) {
        int r = row[e];
        int c = col[e];
        int pos = offs[c] + atomicAdd(&cur[c], 1);
        float norm = dis[r] * dis[c];
        csr[pos] = make_int2(r, __float_as_int(norm));
    }
}

// ======================= scan =======================

__global__ void block_scan_kernel(const int* __restrict__ cnt, int* __restrict__ offs,
                                  int* __restrict__ partials) {
    __shared__ int s[256];
    int t = threadIdx.x;
    int i = blockIdx.x * 256 + t;
    int v = (i < N_NODES) ? cnt[i] : 0;
    s[t] = v;
    __syncthreads();
    for (int d = 1; d < 256; d <<= 1) {
        int u = (t >= d) ? s[t - d] : 0;
        __syncthreads();
        s[t] += u;
        __syncthreads();
    }
    if (i < N_NODES) offs[i] = s[t] - v;
    if (t == 255) partials[blockIdx.x] = s[t];
}

__global__ void scan_partials_kernel(int* __restrict__ partials) {
    __shared__ int s[256];
    int t = threadIdx.x;
    int v = (t < NB_SCAN) ? partials[t] : 0;
    s[t] = v;
    __syncthreads();
    for (int d = 1; d < 256; d <<= 1) {
        int u = (t >= d) ? s[t - d] : 0;
        __syncthreads();
        s[t] += u;
        __syncthreads();
    }
    if (t < NB_SCAN) partials[t] = s[t] - v;
}

__global__ void add_off_kernel(int* __restrict__ offs, const int* __restrict__ partials) {
    int i = blockIdx.x * 256 + threadIdx.x;
    if (i < N_NODES) offs[i] += partials[blockIdx.x];
}

// ======================= gemm: 64x64 tile, 4x4 register tile =======================
// block = 256 threads handles 64 nodes x 64 features.
// LDS: Xs padded to 68 floats/row (2-way max bank aliasing = free), Ws 64x64.
__global__ __launch_bounds__(256) void gemm_kernel(const float* __restrict__ x,
                                                   const float* __restrict__ W,
                                                   float* __restrict__ h) {
    __shared__ float Xs[64][68];  // 17.4 KB
    __shared__ float Ws[64][64];  // 16 KB
    int t = threadIdx.x;
    int n0 = blockIdx.x * 64;

    // stage W: 4096 floats = 4 float4 per thread, coalesced
    const float4* W4 = (const float4*)W;
    float4* Ws4 = (float4*)Ws;
#pragma unroll
    for (int i = 0; i < 4; ++i) Ws4[t + i * 256] = W4[t + i * 256];

    // stage X rows n0..n0+63 (guard tail block)
    const float4* x4 = (const float4*)(x + (size_t)n0 * D);
#pragma unroll
    for (int i = 0; i < 4; ++i) {
        int f = t + i * 256;           // 0..1023 float4s
        int r = f >> 4;                // row in tile (16 float4 per row)
        int c = (f & 15) << 2;
        float4 v = make_float4(0.f, 0.f, 0.f, 0.f);
        if (n0 + r < N_NODES) v = x4[f];
        Xs[r][c] = v.x; Xs[r][c + 1] = v.y; Xs[r][c + 2] = v.z; Xs[r][c + 3] = v.w;
    }
    __syncthreads();

    int tx = t & 15;   // feature group: cols tx*4..tx*4+3
    int ty = t >> 4;   // node group:    rows ty*4..ty*4+3
    float acc[4][4] = {};
#pragma unroll
    for (int k = 0; k < D; ++k) {
        float a[4], b[4];
#pragma unroll
        for (int i = 0; i < 4; ++i) a[i] = Xs[ty * 4 + i][k];
#pragma unroll
        for (int jj = 0; jj < 4; ++jj) b[jj] = Ws[k][tx * 4 + jj];
#pragma unroll
        for (int i = 0; i < 4; ++i)
#pragma unroll
            for (int jj = 0; jj < 4; ++jj)
                acc[i][jj] = fmaf(a[i], b[jj], acc[i][jj]);
    }

    float4* h4 = (float4*)(h + (size_t)n0 * D);
#pragma unroll
    for (int i = 0; i < 4; ++i) {
        int r = ty * 4 + i;
        if (n0 + r < N_NODES) {
            float4 v = make_float4(acc[i][0], acc[i][1], acc[i][2], acc[i][3]);
            h4[r * 16 + tx] = v;
        }
    }
}

// ======================= gather: wave per node, x4 unrolled MLP =======================
__global__ void gather_kernel(const int* __restrict__ offs, const int* __restrict__ cnt,
                              const int2* __restrict__ csr,
                              const float* __restrict__ h, const float* __restrict__ dis,
                              const float* __restrict__ bias,
                              float* __restrict__ out) {
    int wave = threadIdx.x >> 6;
    int j = threadIdx.x & 63;
    int n = blockIdx.x * 4 + wave;
    if (n >= N_NODES) return;

    float d = dis[n];
    float acc0 = bias[j] + h[n * D + j] * d * d;  // self-loop term
    float acc1 = 0.f, acc2 = 0.f, acc3 = 0.f;

    int beg = offs[n];
    int m = cnt[n];
    for (int base = 0; base < m; base += 64) {
        int take = min(64, m - base);
        int2 e = make_int2(0, 0);
        if (j < take) e = csr[beg + base + j];  // coalesced batch load
        int i = 0;
        for (; i + 4 <= take; i += 4) {
            int   r0 = __shfl(e.x, i);     float w0 = __int_as_float(__shfl(e.y, i));
            int   r1 = __shfl(e.x, i + 1); float w1 = __int_as_float(__shfl(e.y, i + 1));
            int   r2 = __shfl(e.x, i + 2); float w2 = __int_as_float(__shfl(e.y, i + 2));
            int   r3 = __shfl(e.x, i + 3); float w3 = __int_as_float(__shfl(e.y, i + 3));
            float v0 = h[r0 * D + j];      // 4 independent loads in flight
            float v1 = h[r1 * D + j];
            float v2 = h[r2 * D + j];
            float v3 = h[r3 * D + j];
            acc0 = fmaf(v0, w0, acc0);
            acc1 = fmaf(v1, w1, acc1);
            acc2 = fmaf(v2, w2, acc2);
            acc3 = fmaf(v3, w3, acc3);
        }
        for (; i < take; ++i) {
            int r = __shfl(e.x, i);
            float w = __int_as_float(__shfl(e.y, i));
            acc1 = fmaf(h[r * D + j], w, acc1);
        }
    }
    out[n * D + j] = (acc0 + acc1) + (acc2 + acc3);
}

// ======================= launch =======================

extern "C" void kernel_launch(void* const* d_in, const int* in_sizes, int n_in,
                              void* d_out, int out_size, void* d_ws, size_t ws_size,
                              hipStream_t stream) {
    const float* x    = (const float*)d_in[0];
    const int*   ei   = (const int*)d_in[1];
    const float* W    = (const float*)d_in[2];
    const float* bias = (const float*)d_in[3];
    float* out = (float*)d_out;

    const int* row = ei;
    const int* col = ei + N_EDGES;

    char* ws = (char*)d_ws;
    float*    dis      = (float*)(ws + 0);
    int*      cnt      = (int*)(ws + 200000);
    int*      cur      = (int*)(ws + 400000);
    int*      offs     = (int*)(ws + 600000);
    int*      partials = (int*)(ws + 800000);
    int2*     csr      = (int2*)(ws + 801024);
    float*    h        = (float*)(ws + 7201024);
    unsigned* bh       = (unsigned*)(ws + 20001024);
    unsigned* bs       = (unsigned*)(ws + 32801024);

    const size_t WS_NEEDED = 45601024;

    if (ws_size >= WS_NEEDED) {
        hist_priv_kernel<<<2 * B_SLICE, 1024, 0, stream>>>(ei, bh);
        reduce_kernel<<<(2 * PACK + 255) / 256, 256, 0, stream>>>(bh, dis, cnt);
        block_scan_kernel<<<NB_SCAN, 256, 0, stream>>>(cnt, offs, partials);
        scan_partials_kernel<<<1, 256, 0, stream>>>(partials);
        add_off_kernel<<<NB_SCAN, 256, 0, stream>>>(offs, partials);
        colscan_kernel<<<(PACK + 255) / 256, 256, 0, stream>>>(bh, offs, bs);
        bucket_det_kernel<<<2 * B_SLICE, 1024, 0, stream>>>(ei, dis, bs, csr);
    } else {
        int* degi = (int*)dis;
        hipMemsetAsync(ws, 0, 600000, stream);
        hist_kernel<<<(N_EDGES + 255) / 256, 256, 0, stream>>>(row, col, degi, cnt);
        dis_kernel<<<(N_NODES + 255) / 256, 256, 0, stream>>>(degi);
        block_scan_kernel<<<NB_SCAN, 256, 0, stream>>>(cnt, offs, partials);
        scan_partials_kernel<<<1, 256, 0, stream>>>(partials);
        add_off_kernel<<<NB_SCAN, 256, 0, stream>>>(offs, partials);
        bucket_kernel<<<(N_EDGES + 255) / 256, 256, 0, stream>>>(row, col, dis, offs, cur, csr);
    }

    gemm_kernel<<<(N_NODES + 63) / 64, 256, 0, stream>>>(x, W, h);
    gather_kernel<<<(N_NODES + 3) / 4, 256, 0, stream>>>(offs, cnt, csr, h, dis, bias, out);
}